// Round 7
// baseline (1134.953 us; speedup 1.0000x reference)
//
#include <hip/hip_runtime.h>
#include <math.h>

// DigitCaps dynamic routing. B=512, I=1152, K=8, C=10, D=16, 3 iters.
//
// R7: NO u_hat materialization. Three fused passes recompute u_hat rows from
// L2-resident W_t (5.9 MB) + u (19 MB). Wave = (4 b, 36-i chunk), lane =
// cd-quad (40/64 active). W row double-buffered in registers (one-i lookahead,
// fixed buffers). Softmax in-register: 2 shfl logit reduce + masked 4-step
// xor butterfly. i-chunks XCD-pinned (blockIdx%8 == ch%8) so each XCD's L2
// holds its 740 KB W slice + 2.4 MB u slice. s via global f32 atomics.
//
// History: R5/R6 materialized bf16 u_hat = 333 us, producer ILP-bound at
// 1.7 TB/s / 33% VALU. Fused floor removes 570 MB of HBM traffic per call.

#define UHQ 40          // float4 quads per (b,i) row
#define NCHK 32         // i-chunks
#define NI   36         // i per chunk (1152/32)
#define BPW  4          // b per wave

__device__ __forceinline__ float dot8(const float4 w0, const float4 w1,
                                      const float4 ua, const float4 ub) {
    return w0.x*ua.x + w0.y*ua.y + w0.z*ua.z + w0.w*ua.w
         + w1.x*ub.x + w1.y*ub.y + w1.z*ub.z + w1.w*ub.w;
}

// W transpose: original f4 quad (i, q, j) [floats 32q+4j] -> Wt f4 index
// i*320 + j*40 + q, so for fixed (i,j) the 40 lanes read 640 B contiguous.
__global__ void transpose_W(const float4* __restrict__ W4, float4* __restrict__ Wt4)
{
    int tid = blockIdx.x * 256 + threadIdx.x;
    if (tid >= 1152 * 320) return;
    int i = tid / 320, r = tid - i * 320;
    int q = r >> 3, j = r & 7;
    Wt4[i * 320 + j * 40 + q] = W4[tid];
}

__device__ __forceinline__ void loadW(float4* w4, const float4* __restrict__ WtB,
                                      int i, int q, bool act) {
    if (act) {
        const float4* wb = WtB + (size_t)i * 320 + q;
        #pragma unroll
        for (int j = 0; j < 8; ++j) w4[j] = wb[j * 40];
    }
}

template <int PASS>
__device__ __forceinline__ void body(const float4* __restrict__ w4,
                                     const float* __restrict__ u,
                                     const float4* __restrict__ va,
                                     float4* __restrict__ sacc,
                                     int b0, int i, bool act)
{
    #pragma unroll
    for (int bb = 0; bb < BPW; ++bb) {
        const int b = b0 + bb;
        const float4* up = (const float4*)(u + ((size_t)b * 1152 + i) * 8);
        const float4 ua = up[0], ub = up[1];   // wave-uniform broadcast
        float4 uh;
        uh.x = dot8(w4[0], w4[1], ua, ub);
        uh.y = dot8(w4[2], w4[3], ua, ub);
        uh.z = dot8(w4[4], w4[5], ua, ub);
        uh.w = dot8(w4[6], w4[7], ua, ub);
        if (PASS == 0) {
            sacc[bb].x += uh.x; sacc[bb].y += uh.y;
            sacc[bb].z += uh.z; sacc[bb].w += uh.w;
        } else {
            // logit for this lane's c (=q>>2): 4-lane segmented reduction
            float pd = uh.x*va[bb].x + uh.y*va[bb].y + uh.z*va[bb].z + uh.w*va[bb].w;
            pd += __shfl_xor(pd, 1);
            pd += __shfl_xor(pd, 2);
            const float e = act ? __expf(pd) : 0.0f;   // |logit| small: no max-sub
            float sm = e;
            sm += __shfl_xor(sm, 4);
            sm += __shfl_xor(sm, 8);
            sm += __shfl_xor(sm, 16);
            sm += __shfl_xor(sm, 32);
            const float coef = e / sm;
            sacc[bb].x += coef * uh.x; sacc[bb].y += coef * uh.y;
            sacc[bb].z += coef * uh.z; sacc[bb].w += coef * uh.w;
        }
    }
}

template <int PASS>
__global__ __launch_bounds__(256, 4)
void fused_pass(const float* __restrict__ u, const float* __restrict__ Wt,
                const float* __restrict__ v0g, const float* __restrict__ v1g,
                float* __restrict__ sg)
{
    const int t = threadIdx.x, lane = t & 63, wv = t >> 6;
    const int gid = blockIdx.x;
    const int bg  = gid >> 5;            // 0..31  (16 b per block)
    const int ch  = gid & 31;            // 0..31; blockIdx%8 == ch%8 -> XCD pin
    const int b0  = bg * 16 + wv * BPW;  // 4 b per wave
    const int i0  = ch * NI;
    const int q   = lane;
    const bool act = (q < UHQ);
    const float4* WtB = (const float4*)Wt;

    float4 va[BPW];
    #pragma unroll
    for (int bb = 0; bb < BPW; ++bb) va[bb] = make_float4(0.f, 0.f, 0.f, 0.f);
    if (PASS >= 1 && act) {
        #pragma unroll
        for (int bb = 0; bb < BPW; ++bb) {
            va[bb] = ((const float4*)v0g)[(size_t)(b0 + bb) * UHQ + q];
            if (PASS == 2) {
                const float4 vb = ((const float4*)v1g)[(size_t)(b0 + bb) * UHQ + q];
                va[bb].x += vb.x; va[bb].y += vb.y;
                va[bb].z += vb.z; va[bb].w += vb.w;
            }
        }
    }

    float4 sacc[BPW];
    #pragma unroll
    for (int bb = 0; bb < BPW; ++bb) sacc[bb] = make_float4(0.f, 0.f, 0.f, 0.f);

    // software-pipelined i loop: one-i W lookahead, fixed double buffers
    float4 wA[8], wB[8];
    loadW(wA, WtB, i0, q, act);
    #pragma unroll 1
    for (int ii = 0; ii < NI; ii += 2) {
        loadW(wB, WtB, i0 + ii + 1, q, act);
        body<PASS>(wA, u, va, sacc, b0, i0 + ii, act);
        if (ii + 2 < NI) loadW(wA, WtB, i0 + ii + 2, q, act);
        body<PASS>(wB, u, va, sacc, b0, i0 + ii + 1, act);
    }

    if (act) {
#if defined(__HIP_DEVICE_COMPILE__)
        #pragma unroll
        for (int bb = 0; bb < BPW; ++bb) {
            const float sc = (PASS == 0) ? 0.1f : 1.0f;
            float* sp = sg + (size_t)(b0 + bb) * 160 + q * 4;
            unsafeAtomicAdd(sp + 0, sc * sacc[bb].x);
            unsafeAtomicAdd(sp + 1, sc * sacc[bb].y);
            unsafeAtomicAdd(sp + 2, sc * sacc[bb].z);
            unsafeAtomicAdd(sp + 3, sc * sacc[bb].w);
        }
#endif
    }
}

// ---------------- squash ----------------
__global__ void squash_scale(const float* __restrict__ s, float* __restrict__ vout,
                             float scale)
{
    int r = blockIdx.x * 256 + threadIdx.x;
    if (r >= 512 * 10) return;
    const float* sp = s + (size_t)r * 16;
    float sv[16];
    float ns = 0.0f;
    #pragma unroll
    for (int d = 0; d < 16; ++d) {
        float x = sp[d] * scale;
        sv[d] = x;
        ns += x * x;
    }
    float sc = ns / ((1.0f + ns) * (sqrtf(ns) + 1e-8f));
    float* o = vout + (size_t)r * 16;
    #pragma unroll
    for (int d = 0; d < 16; ++d) o[d] = sv[d] * sc;
}

// ---------------- tiny-ws fallback (R3-style): thread owns (b,c) ----------------
template <int PASS>
__global__ __launch_bounds__(256, 4)
void pass_fb(const float* __restrict__ u, const float* __restrict__ W,
             const float* __restrict__ v0g, const float* __restrict__ v1g,
             float* __restrict__ s_atomic)
{
    const int t    = threadIdx.x;
    const int lane = t & 63;
    const int wv   = t >> 6;
    const int bsub = lane / 10;
    const int c    = lane - bsub * 10;
    const bool lane_ok = (bsub < 6);
    const int b    = blockIdx.y * 24 + wv * 6 + bsub;
    const bool valid = lane_ok && (b < 512);
    const int bc   = valid ? b : 511;
    const int base = lane_ok ? bsub * 10 : 0;
    const int i0   = blockIdx.x * 24;

    float v[16];
    #pragma unroll
    for (int d = 0; d < 16; ++d) v[d] = 0.0f;
    if (PASS >= 1) {
        const float* vp = v0g + ((size_t)bc * 10 + c) * 16;
        #pragma unroll
        for (int d = 0; d < 16; ++d) v[d] = vp[d];
        if (PASS >= 2) {
            const float* vq = v1g + ((size_t)bc * 10 + c) * 16;
            #pragma unroll
            for (int d = 0; d < 16; ++d) v[d] += vq[d];
        }
    }

    float s_acc[16];
    #pragma unroll
    for (int d = 0; d < 16; ++d) s_acc[d] = 0.0f;

    for (int ii = 0; ii < 24; ++ii) {
        const int i = i0 + ii;
        const float4* up = (const float4*)(u + ((size_t)bc * 1152 + i) * 8);
        const float4 ua = up[0];
        const float4 ub = up[1];
        const float* Wp = W + ((size_t)i * 10 + c) * 128;

        float h[16];
        #pragma unroll
        for (int d = 0; d < 16; ++d) {
            const float4* wp = (const float4*)(Wp + d * 8);
            h[d] = dot8(wp[0], wp[1], ua, ub);
        }

        if (PASS == 0) {
            #pragma unroll
            for (int d = 0; d < 16; ++d) s_acc[d] += h[d];
        } else {
            float lg = 0.0f;
            #pragma unroll
            for (int d = 0; d < 16; ++d) lg += h[d] * v[d];
            float lj[10];
            #pragma unroll
            for (int j = 0; j < 10; ++j) lj[j] = __shfl(lg, base + j);
            float m = lj[0];
            #pragma unroll
            for (int j = 1; j < 10; ++j) m = fmaxf(m, lj[j]);
            float sum = 0.0f;
            #pragma unroll
            for (int j = 0; j < 10; ++j) sum += __expf(lj[j] - m);
            const float coef = __expf(lg - m) / sum;
            #pragma unroll
            for (int d = 0; d < 16; ++d) s_acc[d] += coef * h[d];
        }
    }
    if (PASS == 0) {
        #pragma unroll
        for (int d = 0; d < 16; ++d) s_acc[d] *= 0.1f;
    }
    if (valid) {
#if defined(__HIP_DEVICE_COMPILE__)
        #pragma unroll
        for (int d = 0; d < 16; ++d)
            unsafeAtomicAdd(&s_atomic[((size_t)b * 10 + c) * 16 + d], s_acc[d]);
#endif
    }
}

extern "C" void kernel_launch(void* const* d_in, const int* in_sizes, int n_in,
                              void* d_out, int out_size, void* d_ws, size_t ws_size,
                              hipStream_t stream)
{
    const float* u = (const float*)d_in[0];   // [512,1152,8]
    const float* W = (const float*)d_in[1];   // [1152,10,16,8]
    float* out = (float*)d_out;               // [512,10,16]

    float* v0 = (float*)d_ws;
    float* v1 = v0 + 81920;
    float* s0 = v1 + 81920;
    float* s1 = s0 + 81920;
    float* s2 = s1 + 81920;
    float* wt = s2 + 81920;                   // 1,474,560 f32 (5.9 MB)

    const size_t head = (size_t)5 * 81920 * sizeof(float);          // 1.64 MB
    const size_t wtsz = (size_t)1152 * 1280 * sizeof(float);        // 5.90 MB

    hipMemsetAsync(s0, 0, (size_t)3 * 81920 * sizeof(float), stream);

    dim3 blk(256);

    if (ws_size >= head + wtsz) {
        transpose_W<<<1440, blk, 0, stream>>>((const float4*)W, (float4*)wt);
        fused_pass<0><<<1024, blk, 0, stream>>>(u, wt, nullptr, nullptr, s0);
        squash_scale<<<20, blk, 0, stream>>>(s0, v0, 1.0f);
        fused_pass<1><<<1024, blk, 0, stream>>>(u, wt, v0, nullptr, s1);
        squash_scale<<<20, blk, 0, stream>>>(s1, v1, 1.0f);
        fused_pass<2><<<1024, blk, 0, stream>>>(u, wt, v0, v1, s2);
        squash_scale<<<20, blk, 0, stream>>>(s2, out, 1.0f);
    } else {
        dim3 grid(48, 22);
        pass_fb<0><<<grid, blk, 0, stream>>>(u, W, nullptr, nullptr, s0);
        squash_scale<<<20, blk, 0, stream>>>(s0, v0, 1.0f);
        pass_fb<1><<<grid, blk, 0, stream>>>(u, W, v0, nullptr, s1);
        squash_scale<<<20, blk, 0, stream>>>(s1, v1, 1.0f);
        pass_fb<2><<<grid, blk, 0, stream>>>(u, W, v0, v1, s2);
        squash_scale<<<20, blk, 0, stream>>>(s2, out, 1.0f);
    }
}

// Round 8
// 1124.316 us; speedup vs baseline: 1.0095x; 1.0095x over previous
//
#include <hip/hip_runtime.h>
#include <math.h>

// DigitCaps dynamic routing. B=512, I=1152, K=8, C=10, D=16, 3 iters.
//
// R8: fused passes (no u_hat buffer) with STRUCTURAL reuse:
//  - W_t staged in LDS in 4-i slabs (20 KB, double-buffered via register
//    prefetch, one barrier per slab). W read from global once per block per i
//    -> 94 MB logical traffic/pass (R7: 755 MB logical, 690 MB FETCH —
//    L2 conflict-thrashed, the XCD-pin assumption failed).
//  - 8 b per wave (R7: 4) under __launch_bounds__(256,2) (VGPR cap 256).
//  - ZERO global atomics (R7: 2.6M cross-XCD atomics -> 573 MB WRITE):
//    non-atomic per-chunk partials + reduce_squash (R3-proven).
//  - softmax: register/shuffle only (R7-validated: quad-reduce + masked
//    xor butterfly; no max-subtraction, logits are small).

#define NCHK 32         // i-chunks
#define NI   36         // i per chunk
#define SLAB 4          // i per LDS slab
#define NSLAB (NI / SLAB)   // 9
#define BPW  8          // b per wave
#define UHQ  40         // active lanes (cd-quads)

__device__ __forceinline__ float dot8(const float4 w0, const float4 w1,
                                      const float4 ua, const float4 ub) {
    return w0.x*ua.x + w0.y*ua.y + w0.z*ua.z + w0.w*ua.w
         + w1.x*ub.x + w1.y*ub.y + w1.z*ub.z + w1.w*ub.w;
}

// W transpose: f4 quad (i, q, j) [floats 32q+4j] -> Wt f4 idx i*320 + j*40 + q.
__global__ void transpose_W(const float4* __restrict__ W4, float4* __restrict__ Wt4)
{
    int tid = blockIdx.x * 256 + threadIdx.x;
    if (tid >= 1152 * 320) return;
    int i = tid / 320, r = tid - i * 320;
    int q = r >> 3, j = r & 7;
    Wt4[i * 320 + j * 40 + q] = W4[tid];
}

template <int PASS>
__global__ __launch_bounds__(256, 2)
void fused_pass(const float* __restrict__ u, const float* __restrict__ Wt,
                const float* __restrict__ v0g, const float* __restrict__ v1g,
                float* __restrict__ part)
{
    __shared__ float4 slab[2][SLAB * 320];   // 2 x 20 KB

    const int t = threadIdx.x, lane = t & 63, wv = t >> 6;
    const int gid = blockIdx.x;
    const int bg  = gid >> 5;            // 0..15 (32 b per block)
    const int ch  = gid & 31;            // 0..31
    const int b0  = bg * 32 + wv * BPW;  // 8 b per wave
    const int i0  = ch * NI;
    const int q   = lane;
    const bool act = (q < UHQ);
    const float4* Wt4 = (const float4*)Wt;

    // v (i-invariant) per b, in registers
    float4 va[BPW];
    #pragma unroll
    for (int bb = 0; bb < BPW; ++bb) va[bb] = make_float4(0.f, 0.f, 0.f, 0.f);
    if (PASS >= 1 && act) {
        #pragma unroll
        for (int bb = 0; bb < BPW; ++bb) {
            va[bb] = ((const float4*)v0g)[(size_t)(b0 + bb) * UHQ + q];
            if (PASS == 2) {
                const float4 vb = ((const float4*)v1g)[(size_t)(b0 + bb) * UHQ + q];
                va[bb].x += vb.x; va[bb].y += vb.y;
                va[bb].z += vb.z; va[bb].w += vb.w;
            }
        }
    }

    float4 sacc[BPW];
    #pragma unroll
    for (int bb = 0; bb < BPW; ++bb) sacc[bb] = make_float4(0.f, 0.f, 0.f, 0.f);

    // prologue: stage slab 0 (4 i = 1280 f4, 5 per thread)
    {
        const size_t base = (size_t)i0 * 320;
        #pragma unroll
        for (int k = 0; k < 5; ++k) slab[0][t + 256 * k] = Wt4[base + t + 256 * k];
    }
    __syncthreads();

    int cur = 0;
    #pragma unroll 1
    for (int s = 0; s < NSLAB; ++s) {
        // prefetch next slab into registers (latency overlapped with compute)
        float4 pre[5];
        const bool more = (s + 1 < NSLAB);
        if (more) {
            const size_t base = (size_t)(i0 + (s + 1) * SLAB) * 320;
            #pragma unroll
            for (int k = 0; k < 5; ++k) pre[k] = Wt4[base + t + 256 * k];
        }

        #pragma unroll
        for (int il = 0; il < SLAB; ++il) {
            const int i = i0 + s * SLAB + il;
            float4 w4[8];
            if (act) {
                #pragma unroll
                for (int j = 0; j < 8; ++j) w4[j] = slab[cur][il * 320 + j * 40 + q];
            }
            #pragma unroll
            for (int bb = 0; bb < BPW; ++bb) {
                const int b = b0 + bb;
                const float4* up = (const float4*)(u + ((size_t)b * 1152 + i) * 8);
                const float4 ua = up[0], ub = up[1];   // wave-uniform broadcast
                float4 uh;
                uh.x = dot8(w4[0], w4[1], ua, ub);
                uh.y = dot8(w4[2], w4[3], ua, ub);
                uh.z = dot8(w4[4], w4[5], ua, ub);
                uh.w = dot8(w4[6], w4[7], ua, ub);
                if (PASS == 0) {
                    sacc[bb].x += uh.x; sacc[bb].y += uh.y;
                    sacc[bb].z += uh.z; sacc[bb].w += uh.w;
                } else {
                    float pd = uh.x*va[bb].x + uh.y*va[bb].y
                             + uh.z*va[bb].z + uh.w*va[bb].w;
                    pd += __shfl_xor(pd, 1);
                    pd += __shfl_xor(pd, 2);           // full dot for this lane's c
                    const float e = act ? __expf(pd) : 0.0f;
                    float sm = e;
                    sm += __shfl_xor(sm, 4);
                    sm += __shfl_xor(sm, 8);
                    sm += __shfl_xor(sm, 16);
                    sm += __shfl_xor(sm, 32);          // = sum_c e_c (one lane/c per mod-4 class)
                    const float coef = e / sm;
                    sacc[bb].x += coef * uh.x; sacc[bb].y += coef * uh.y;
                    sacc[bb].z += coef * uh.z; sacc[bb].w += coef * uh.w;
                }
            }
        }

        if (more) {
            #pragma unroll
            for (int k = 0; k < 5; ++k) slab[cur ^ 1][t + 256 * k] = pre[k];
        }
        __syncthreads();
        cur ^= 1;
    }

    // epilogue: non-atomic per-chunk partials, coalesced f4 stores
    if (act) {
        const float sc = (PASS == 0) ? 0.1f : 1.0f;
        #pragma unroll
        for (int bb = 0; bb < BPW; ++bb) {
            float4 o;
            o.x = sc * sacc[bb].x; o.y = sc * sacc[bb].y;
            o.z = sc * sacc[bb].z; o.w = sc * sacc[bb].w;
            ((float4*)part)[((size_t)ch * 512 + b0 + bb) * UHQ + q] = o;
        }
    }
}

// Sum NCHK partials and squash. 8 b-rows per block, grid 64.
__global__ void reduce_squash(const float* __restrict__ part, float* __restrict__ vout)
{
    __shared__ float acc_s[8 * 160];
    const int t  = threadIdx.x;
    const int b0 = blockIdx.x * 8;

    float acc[5] = {0.f, 0.f, 0.f, 0.f, 0.f};
    for (int ch = 0; ch < NCHK; ++ch) {
        const float* p = part + ((size_t)ch * 512 + b0) * 160;
        #pragma unroll
        for (int j = 0; j < 5; ++j) acc[j] += p[t + 256 * j];
    }
    #pragma unroll
    for (int j = 0; j < 5; ++j) acc_s[t + 256 * j] = acc[j];
    __syncthreads();

    if (t < 80) {   // 8 b x 10 c rows
        float sv[16];
        float ns = 0.0f;
        #pragma unroll
        for (int d = 0; d < 16; ++d) {
            float x = acc_s[t * 16 + d];
            sv[d] = x;
            ns += x * x;
        }
        float scale = ns / ((1.0f + ns) * (sqrtf(ns) + 1e-8f));
        float* o = vout + ((size_t)b0 * 10 + t) * 16;
        #pragma unroll
        for (int d = 0; d < 16; ++d) o[d] = sv[d] * scale;
    }
}

// ---------------- tiny-ws fallback (R3-style) ----------------
__global__ void squash_only(const float* __restrict__ s, float* __restrict__ vout)
{
    int r = blockIdx.x * 256 + threadIdx.x;
    if (r >= 512 * 10) return;
    const float* sp = s + (size_t)r * 16;
    float sv[16];
    float ns = 0.0f;
    #pragma unroll
    for (int d = 0; d < 16; ++d) {
        float x = sp[d];
        sv[d] = x;
        ns += x * x;
    }
    float scale = ns / ((1.0f + ns) * (sqrtf(ns) + 1e-8f));
    float* o = vout + (size_t)r * 16;
    #pragma unroll
    for (int d = 0; d < 16; ++d) o[d] = sv[d] * scale;
}

template <int PASS>
__global__ __launch_bounds__(256, 4)
void pass_fb(const float* __restrict__ u, const float* __restrict__ W,
             const float* __restrict__ v0g, const float* __restrict__ v1g,
             float* __restrict__ s_atomic)
{
    const int t    = threadIdx.x;
    const int lane = t & 63;
    const int wv   = t >> 6;
    const int bsub = lane / 10;
    const int c    = lane - bsub * 10;
    const bool lane_ok = (bsub < 6);
    const int b    = blockIdx.y * 24 + wv * 6 + bsub;
    const bool valid = lane_ok && (b < 512);
    const int bc   = valid ? b : 511;
    const int base = lane_ok ? bsub * 10 : 0;
    const int i0   = blockIdx.x * 24;

    float v[16];
    #pragma unroll
    for (int d = 0; d < 16; ++d) v[d] = 0.0f;
    if (PASS >= 1) {
        const float* vp = v0g + ((size_t)bc * 10 + c) * 16;
        #pragma unroll
        for (int d = 0; d < 16; ++d) v[d] = vp[d];
        if (PASS >= 2) {
            const float* vq = v1g + ((size_t)bc * 10 + c) * 16;
            #pragma unroll
            for (int d = 0; d < 16; ++d) v[d] += vq[d];
        }
    }

    float s_acc[16];
    #pragma unroll
    for (int d = 0; d < 16; ++d) s_acc[d] = 0.0f;

    for (int ii = 0; ii < 24; ++ii) {
        const int i = i0 + ii;
        const float4* up = (const float4*)(u + ((size_t)bc * 1152 + i) * 8);
        const float4 ua = up[0];
        const float4 ub = up[1];
        const float* Wp = W + ((size_t)i * 10 + c) * 128;

        float h[16];
        #pragma unroll
        for (int d = 0; d < 16; ++d) {
            const float4* wp = (const float4*)(Wp + d * 8);
            h[d] = dot8(wp[0], wp[1], ua, ub);
        }

        if (PASS == 0) {
            #pragma unroll
            for (int d = 0; d < 16; ++d) s_acc[d] += h[d];
        } else {
            float lg = 0.0f;
            #pragma unroll
            for (int d = 0; d < 16; ++d) lg += h[d] * v[d];
            float lj[10];
            #pragma unroll
            for (int j = 0; j < 10; ++j) lj[j] = __shfl(lg, base + j);
            float m = lj[0];
            #pragma unroll
            for (int j = 1; j < 10; ++j) m = fmaxf(m, lj[j]);
            float sum = 0.0f;
            #pragma unroll
            for (int j = 0; j < 10; ++j) sum += __expf(lj[j] - m);
            const float coef = __expf(lg - m) / sum;
            #pragma unroll
            for (int d = 0; d < 16; ++d) s_acc[d] += coef * h[d];
        }
    }
    if (PASS == 0) {
        #pragma unroll
        for (int d = 0; d < 16; ++d) s_acc[d] *= 0.1f;
    }
    if (valid) {
#if defined(__HIP_DEVICE_COMPILE__)
        #pragma unroll
        for (int d = 0; d < 16; ++d)
            unsafeAtomicAdd(&s_atomic[((size_t)b * 10 + c) * 16 + d], s_acc[d]);
#endif
    }
}

extern "C" void kernel_launch(void* const* d_in, const int* in_sizes, int n_in,
                              void* d_out, int out_size, void* d_ws, size_t ws_size,
                              hipStream_t stream)
{
    const float* u = (const float*)d_in[0];   // [512,1152,8]
    const float* W = (const float*)d_in[1];   // [1152,10,16,8]
    float* out = (float*)d_out;               // [512,10,16]

    float* v0 = (float*)d_ws;                          // 81920 f32
    float* v1 = v0 + 81920;                            // 81920 f32
    float* wt = v1 + 81920;                            // 1,474,560 f32 (5.9 MB)
    float* part = wt + (size_t)1152 * 1280;            // 32*512*160 f32 (10.5 MB)

    const size_t need = ((size_t)2 * 81920 + (size_t)1152 * 1280
                         + (size_t)NCHK * 512 * 160) * sizeof(float);   // ~17 MB

    dim3 blk(256);

    if (ws_size >= need) {
        transpose_W<<<1440, blk, 0, stream>>>((const float4*)W, (float4*)wt);
        fused_pass<0><<<512, blk, 0, stream>>>(u, wt, nullptr, nullptr, part);
        reduce_squash<<<64, blk, 0, stream>>>(part, v0);
        fused_pass<1><<<512, blk, 0, stream>>>(u, wt, v0, nullptr, part);
        reduce_squash<<<64, blk, 0, stream>>>(part, v1);
        fused_pass<2><<<512, blk, 0, stream>>>(u, wt, v0, v1, part);
        reduce_squash<<<64, blk, 0, stream>>>(part, out);
    } else {
        float* s0 = wt;                   // reuse low ws as atomic s buffers
        float* s1 = s0 + 81920;
        float* s2 = s1 + 81920;
        hipMemsetAsync(s0, 0, (size_t)3 * 81920 * sizeof(float), stream);
        dim3 grid(48, 22);
        pass_fb<0><<<grid, blk, 0, stream>>>(u, W, nullptr, nullptr, s0);
        squash_only<<<20, blk, 0, stream>>>(s0, v0);
        pass_fb<1><<<grid, blk, 0, stream>>>(u, W, v0, nullptr, s1);
        squash_only<<<20, blk, 0, stream>>>(s1, v1);
        pass_fb<2><<<grid, blk, 0, stream>>>(u, W, v0, v1, s2);
        squash_only<<<20, blk, 0, stream>>>(s2, out);
    }
}

// Round 9
// 613.027 us; speedup vs baseline: 1.8514x; 1.8340x over previous
//
#include <hip/hip_runtime.h>
#include <math.h>

// DigitCaps dynamic routing. B=512, I=1152, K=8, C=10, D=16, 3 iters.
//
// R9 = R8 structure (LDS-staged W slabs, zero atomics, per-chunk partials)
// with the register budget actually fitting: 512-thread blocks, 4 b per wave
// (R8's BPW=8 + pre[5] needed ~145 VGPR, compiler capped 128 -> 1.7 GB/pass
// scratch traffic — third spill recurrence). Live state now ~105 VGPR:
// va[4]+sacc[4]+w4[8]+pre[3] f4s. Same 32 b/block, same W traffic, same grid.
//
// SESSION RULE: keep worst-case live VGPRs < ~110 or the compiler spills.

#define NCHK 32         // i-chunks
#define NI   36         // i per chunk
#define SLAB 4          // i per LDS slab
#define NSLAB (NI / SLAB)   // 9
#define BPW  4          // b per wave
#define TPB  512        // 8 waves
#define UHQ  40         // active lanes (cd-quads)

__device__ __forceinline__ float dot8(const float4 w0, const float4 w1,
                                      const float4 ua, const float4 ub) {
    return w0.x*ua.x + w0.y*ua.y + w0.z*ua.z + w0.w*ua.w
         + w1.x*ub.x + w1.y*ub.y + w1.z*ub.z + w1.w*ub.w;
}

// W transpose: f4 quad (i, q, j) [floats 32q+4j] -> Wt f4 idx i*320 + j*40 + q.
__global__ void transpose_W(const float4* __restrict__ W4, float4* __restrict__ Wt4)
{
    int tid = blockIdx.x * 256 + threadIdx.x;
    if (tid >= 1152 * 320) return;
    int i = tid / 320, r = tid - i * 320;
    int q = r >> 3, j = r & 7;
    Wt4[i * 320 + j * 40 + q] = W4[tid];
}

template <int PASS>
__global__ __launch_bounds__(TPB, 2)
void fused_pass(const float* __restrict__ u, const float* __restrict__ Wt,
                const float* __restrict__ v0g, const float* __restrict__ v1g,
                float* __restrict__ part)
{
    __shared__ float4 slab[2][SLAB * 320];   // 2 x 20 KB

    const int t = threadIdx.x, lane = t & 63, wv = t >> 6;
    const int gid = blockIdx.x;
    const int bg  = gid >> 5;            // 0..15 (32 b per block)
    const int ch  = gid & 31;            // 0..31
    const int b0  = bg * 32 + wv * BPW;  // 4 b per wave
    const int i0  = ch * NI;
    const int q   = lane;
    const bool act = (q < UHQ);
    const float4* Wt4 = (const float4*)Wt;

    // v (i-invariant) per b, in registers
    float4 va[BPW];
    #pragma unroll
    for (int bb = 0; bb < BPW; ++bb) va[bb] = make_float4(0.f, 0.f, 0.f, 0.f);
    if (PASS >= 1 && act) {
        #pragma unroll
        for (int bb = 0; bb < BPW; ++bb) {
            va[bb] = ((const float4*)v0g)[(size_t)(b0 + bb) * UHQ + q];
            if (PASS == 2) {
                const float4 vb = ((const float4*)v1g)[(size_t)(b0 + bb) * UHQ + q];
                va[bb].x += vb.x; va[bb].y += vb.y;
                va[bb].z += vb.z; va[bb].w += vb.w;
            }
        }
    }

    float4 sacc[BPW];
    #pragma unroll
    for (int bb = 0; bb < BPW; ++bb) sacc[bb] = make_float4(0.f, 0.f, 0.f, 0.f);

    // prologue: stage slab 0 (1280 f4; 512 threads -> up to 3 each)
    {
        const size_t base = (size_t)i0 * 320;
        #pragma unroll
        for (int k = 0; k < 3; ++k) {
            const int idx = t + TPB * k;
            if (idx < SLAB * 320) slab[0][idx] = Wt4[base + idx];
        }
    }
    __syncthreads();

    int cur = 0;
    #pragma unroll 1
    for (int s = 0; s < NSLAB; ++s) {
        // prefetch next slab into 3 registers (latency overlapped with compute)
        float4 pre[3];
        const bool more = (s + 1 < NSLAB);
        if (more) {
            const size_t base = (size_t)(i0 + (s + 1) * SLAB) * 320;
            #pragma unroll
            for (int k = 0; k < 3; ++k) {
                const int idx = t + TPB * k;
                if (idx < SLAB * 320) pre[k] = Wt4[base + idx];
            }
        }

        #pragma unroll
        for (int il = 0; il < SLAB; ++il) {
            const int i = i0 + s * SLAB + il;
            float4 w4[8];
            if (act) {
                #pragma unroll
                for (int j = 0; j < 8; ++j) w4[j] = slab[cur][il * 320 + j * 40 + q];
            }
            #pragma unroll
            for (int bb = 0; bb < BPW; ++bb) {
                const int b = b0 + bb;
                const float4* up = (const float4*)(u + ((size_t)b * 1152 + i) * 8);
                const float4 ua = up[0], ub = up[1];   // wave-uniform broadcast
                float4 uh;
                uh.x = dot8(w4[0], w4[1], ua, ub);
                uh.y = dot8(w4[2], w4[3], ua, ub);
                uh.z = dot8(w4[4], w4[5], ua, ub);
                uh.w = dot8(w4[6], w4[7], ua, ub);
                if (PASS == 0) {
                    sacc[bb].x += uh.x; sacc[bb].y += uh.y;
                    sacc[bb].z += uh.z; sacc[bb].w += uh.w;
                } else {
                    float pd = uh.x*va[bb].x + uh.y*va[bb].y
                             + uh.z*va[bb].z + uh.w*va[bb].w;
                    pd += __shfl_xor(pd, 1);
                    pd += __shfl_xor(pd, 2);           // full dot for this lane's c
                    const float e = act ? __expf(pd) : 0.0f;
                    float sm = e;
                    sm += __shfl_xor(sm, 4);
                    sm += __shfl_xor(sm, 8);
                    sm += __shfl_xor(sm, 16);
                    sm += __shfl_xor(sm, 32);          // = sum_c e_c
                    const float coef = e / sm;
                    sacc[bb].x += coef * uh.x; sacc[bb].y += coef * uh.y;
                    sacc[bb].z += coef * uh.z; sacc[bb].w += coef * uh.w;
                }
            }
        }

        if (more) {
            #pragma unroll
            for (int k = 0; k < 3; ++k) {
                const int idx = t + TPB * k;
                if (idx < SLAB * 320) slab[cur ^ 1][idx] = pre[k];
            }
        }
        __syncthreads();
        cur ^= 1;
    }

    // epilogue: non-atomic per-chunk partials, coalesced f4 stores
    if (act) {
        const float sc = (PASS == 0) ? 0.1f : 1.0f;
        #pragma unroll
        for (int bb = 0; bb < BPW; ++bb) {
            float4 o;
            o.x = sc * sacc[bb].x; o.y = sc * sacc[bb].y;
            o.z = sc * sacc[bb].z; o.w = sc * sacc[bb].w;
            ((float4*)part)[((size_t)ch * 512 + b0 + bb) * UHQ + q] = o;
        }
    }
}

// Sum NCHK partials and squash. 8 b-rows per block, grid 64.
__global__ void reduce_squash(const float* __restrict__ part, float* __restrict__ vout)
{
    __shared__ float acc_s[8 * 160];
    const int t  = threadIdx.x;
    const int b0 = blockIdx.x * 8;

    float acc[5] = {0.f, 0.f, 0.f, 0.f, 0.f};
    for (int ch = 0; ch < NCHK; ++ch) {
        const float* p = part + ((size_t)ch * 512 + b0) * 160;
        #pragma unroll
        for (int j = 0; j < 5; ++j) acc[j] += p[t + 256 * j];
    }
    #pragma unroll
    for (int j = 0; j < 5; ++j) acc_s[t + 256 * j] = acc[j];
    __syncthreads();

    if (t < 80) {   // 8 b x 10 c rows
        float sv[16];
        float ns = 0.0f;
        #pragma unroll
        for (int d = 0; d < 16; ++d) {
            float x = acc_s[t * 16 + d];
            sv[d] = x;
            ns += x * x;
        }
        float scale = ns / ((1.0f + ns) * (sqrtf(ns) + 1e-8f));
        float* o = vout + ((size_t)b0 * 10 + t) * 16;
        #pragma unroll
        for (int d = 0; d < 16; ++d) o[d] = sv[d] * scale;
    }
}

// ---------------- tiny-ws fallback (R3-style) ----------------
__global__ void squash_only(const float* __restrict__ s, float* __restrict__ vout)
{
    int r = blockIdx.x * 256 + threadIdx.x;
    if (r >= 512 * 10) return;
    const float* sp = s + (size_t)r * 16;
    float sv[16];
    float ns = 0.0f;
    #pragma unroll
    for (int d = 0; d < 16; ++d) {
        float x = sp[d];
        sv[d] = x;
        ns += x * x;
    }
    float scale = ns / ((1.0f + ns) * (sqrtf(ns) + 1e-8f));
    float* o = vout + (size_t)r * 16;
    #pragma unroll
    for (int d = 0; d < 16; ++d) o[d] = sv[d] * scale;
}

__device__ __forceinline__ float dot8p(const float* __restrict__ w,
                                       const float4 ua, const float4 ub) {
    const float4* wp = (const float4*)w;
    const float4 w0 = wp[0];
    const float4 w1 = wp[1];
    return w0.x*ua.x + w0.y*ua.y + w0.z*ua.z + w0.w*ua.w
         + w1.x*ub.x + w1.y*ub.y + w1.z*ub.z + w1.w*ub.w;
}

template <int PASS>
__global__ __launch_bounds__(256, 4)
void pass_fb(const float* __restrict__ u, const float* __restrict__ W,
             const float* __restrict__ v0g, const float* __restrict__ v1g,
             float* __restrict__ s_atomic)
{
    const int t    = threadIdx.x;
    const int lane = t & 63;
    const int wv   = t >> 6;
    const int bsub = lane / 10;
    const int c    = lane - bsub * 10;
    const bool lane_ok = (bsub < 6);
    const int b    = blockIdx.y * 24 + wv * 6 + bsub;
    const bool valid = lane_ok && (b < 512);
    const int bc   = valid ? b : 511;
    const int base = lane_ok ? bsub * 10 : 0;
    const int i0   = blockIdx.x * 24;

    float v[16];
    #pragma unroll
    for (int d = 0; d < 16; ++d) v[d] = 0.0f;
    if (PASS >= 1) {
        const float* vp = v0g + ((size_t)bc * 10 + c) * 16;
        #pragma unroll
        for (int d = 0; d < 16; ++d) v[d] = vp[d];
        if (PASS >= 2) {
            const float* vq = v1g + ((size_t)bc * 10 + c) * 16;
            #pragma unroll
            for (int d = 0; d < 16; ++d) v[d] += vq[d];
        }
    }

    float s_acc[16];
    #pragma unroll
    for (int d = 0; d < 16; ++d) s_acc[d] = 0.0f;

    for (int ii = 0; ii < 24; ++ii) {
        const int i = i0 + ii;
        const float4* up = (const float4*)(u + ((size_t)bc * 1152 + i) * 8);
        const float4 ua = up[0];
        const float4 ub = up[1];
        const float* Wp = W + ((size_t)i * 10 + c) * 128;

        float h[16];
        #pragma unroll
        for (int d = 0; d < 16; ++d) h[d] = dot8p(Wp + d * 8, ua, ub);

        if (PASS == 0) {
            #pragma unroll
            for (int d = 0; d < 16; ++d) s_acc[d] += h[d];
        } else {
            float lg = 0.0f;
            #pragma unroll
            for (int d = 0; d < 16; ++d) lg += h[d] * v[d];
            float lj[10];
            #pragma unroll
            for (int j = 0; j < 10; ++j) lj[j] = __shfl(lg, base + j);
            float m = lj[0];
            #pragma unroll
            for (int j = 1; j < 10; ++j) m = fmaxf(m, lj[j]);
            float sum = 0.0f;
            #pragma unroll
            for (int j = 0; j < 10; ++j) sum += __expf(lj[j] - m);
            const float coef = __expf(lg - m) / sum;
            #pragma unroll
            for (int d = 0; d < 16; ++d) s_acc[d] += coef * h[d];
        }
    }
    if (PASS == 0) {
        #pragma unroll
        for (int d = 0; d < 16; ++d) s_acc[d] *= 0.1f;
    }
    if (valid) {
#if defined(__HIP_DEVICE_COMPILE__)
        #pragma unroll
        for (int d = 0; d < 16; ++d)
            unsafeAtomicAdd(&s_atomic[((size_t)b * 10 + c) * 16 + d], s_acc[d]);
#endif
    }
}

extern "C" void kernel_launch(void* const* d_in, const int* in_sizes, int n_in,
                              void* d_out, int out_size, void* d_ws, size_t ws_size,
                              hipStream_t stream)
{
    const float* u = (const float*)d_in[0];   // [512,1152,8]
    const float* W = (const float*)d_in[1];   // [1152,10,16,8]
    float* out = (float*)d_out;               // [512,10,16]

    float* v0 = (float*)d_ws;                          // 81920 f32
    float* v1 = v0 + 81920;                            // 81920 f32
    float* wt = v1 + 81920;                            // 1,474,560 f32 (5.9 MB)
    float* part = wt + (size_t)1152 * 1280;            // 32*512*160 f32 (10.5 MB)

    const size_t need = ((size_t)2 * 81920 + (size_t)1152 * 1280
                         + (size_t)NCHK * 512 * 160) * sizeof(float);   // ~17 MB

    dim3 blk(256);
    dim3 blk2(TPB);

    if (ws_size >= need) {
        transpose_W<<<1440, blk, 0, stream>>>((const float4*)W, (float4*)wt);
        fused_pass<0><<<512, blk2, 0, stream>>>(u, wt, nullptr, nullptr, part);
        reduce_squash<<<64, blk, 0, stream>>>(part, v0);
        fused_pass<1><<<512, blk2, 0, stream>>>(u, wt, v0, nullptr, part);
        reduce_squash<<<64, blk, 0, stream>>>(part, v1);
        fused_pass<2><<<512, blk2, 0, stream>>>(u, wt, v0, v1, part);
        reduce_squash<<<64, blk, 0, stream>>>(part, out);
    } else {
        float* s0 = wt;                   // reuse low ws as atomic s buffers
        float* s1 = s0 + 81920;
        float* s2 = s1 + 81920;
        hipMemsetAsync(s0, 0, (size_t)3 * 81920 * sizeof(float), stream);
        dim3 grid(48, 22);
        pass_fb<0><<<grid, blk, 0, stream>>>(u, W, nullptr, nullptr, s0);
        squash_only<<<20, blk, 0, stream>>>(s0, v0);
        pass_fb<1><<<grid, blk, 0, stream>>>(u, W, v0, nullptr, s1);
        squash_only<<<20, blk, 0, stream>>>(s1, v1);
        pass_fb<2><<<grid, blk, 0, stream>>>(u, W, v0, v1, s2);
        squash_only<<<20, blk, 0, stream>>>(s2, out);
    }
}

// Round 10
// 389.417 us; speedup vs baseline: 2.9145x; 1.5742x over previous
//
#include <hip/hip_runtime.h>
#include <math.h>

// DigitCaps dynamic routing. B=512, I=1152, K=8, C=10, D=16, 3 iters.
//
// R10 = R9 with ONE change: `#pragma unroll 1` on the il loop.
// R8/R9 post-mortem: full unroll of il let the scheduler hoist all 4
// iterations' w4[8] LDS reads -> 128 VGPRs of w4 alone, ~190 live, allocator
// pegged 128 and spilled ~80 regs per slab iter = the measured 707 MB/pass
// scratch WRITE. Serializing il caps live at ~100 VGPR (w4 32 + va 16 +
// sacc 16 + pre 12 + addressing). ds_read latency per il (~120cyc) is hidden
// by 4 waves/SIMD x ~200cyc VALU per il.
//
// SESSION RULE: watch unrolled loops holding arrays — unroll multiplies
// live registers; keep worst-case live < ~110.

#define NCHK 32         // i-chunks
#define NI   36         // i per chunk
#define SLAB 4          // i per LDS slab
#define NSLAB (NI / SLAB)   // 9
#define BPW  4          // b per wave
#define TPB  512        // 8 waves
#define UHQ  40         // active lanes (cd-quads)

__device__ __forceinline__ float dot8(const float4 w0, const float4 w1,
                                      const float4 ua, const float4 ub) {
    return w0.x*ua.x + w0.y*ua.y + w0.z*ua.z + w0.w*ua.w
         + w1.x*ub.x + w1.y*ub.y + w1.z*ub.z + w1.w*ub.w;
}

// W transpose: f4 quad (i, q, j) [floats 32q+4j] -> Wt f4 idx i*320 + j*40 + q.
__global__ void transpose_W(const float4* __restrict__ W4, float4* __restrict__ Wt4)
{
    int tid = blockIdx.x * 256 + threadIdx.x;
    if (tid >= 1152 * 320) return;
    int i = tid / 320, r = tid - i * 320;
    int q = r >> 3, j = r & 7;
    Wt4[i * 320 + j * 40 + q] = W4[tid];
}

template <int PASS>
__global__ __launch_bounds__(TPB, 2)
void fused_pass(const float* __restrict__ u, const float* __restrict__ Wt,
                const float* __restrict__ v0g, const float* __restrict__ v1g,
                float* __restrict__ part)
{
    __shared__ float4 slab[2][SLAB * 320];   // 2 x 20 KB

    const int t = threadIdx.x, lane = t & 63, wv = t >> 6;
    const int gid = blockIdx.x;
    const int bg  = gid >> 5;            // 0..15 (32 b per block)
    const int ch  = gid & 31;            // 0..31
    const int b0  = bg * 32 + wv * BPW;  // 4 b per wave
    const int i0  = ch * NI;
    const int q   = lane;
    const bool act = (q < UHQ);
    const float4* Wt4 = (const float4*)Wt;

    // v (i-invariant) per b, in registers
    float4 va[BPW];
    #pragma unroll
    for (int bb = 0; bb < BPW; ++bb) va[bb] = make_float4(0.f, 0.f, 0.f, 0.f);
    if (PASS >= 1 && act) {
        #pragma unroll
        for (int bb = 0; bb < BPW; ++bb) {
            va[bb] = ((const float4*)v0g)[(size_t)(b0 + bb) * UHQ + q];
            if (PASS == 2) {
                const float4 vb = ((const float4*)v1g)[(size_t)(b0 + bb) * UHQ + q];
                va[bb].x += vb.x; va[bb].y += vb.y;
                va[bb].z += vb.z; va[bb].w += vb.w;
            }
        }
    }

    float4 sacc[BPW];
    #pragma unroll
    for (int bb = 0; bb < BPW; ++bb) sacc[bb] = make_float4(0.f, 0.f, 0.f, 0.f);

    // prologue: stage slab 0 (1280 f4; 512 threads -> up to 3 each)
    {
        const size_t base = (size_t)i0 * 320;
        #pragma unroll
        for (int k = 0; k < 3; ++k) {
            const int idx = t + TPB * k;
            if (idx < SLAB * 320) slab[0][idx] = Wt4[base + idx];
        }
    }
    __syncthreads();

    int cur = 0;
    #pragma unroll 1
    for (int s = 0; s < NSLAB; ++s) {
        // prefetch next slab into 3 registers (latency overlapped with compute)
        float4 pre[3];
        const bool more = (s + 1 < NSLAB);
        if (more) {
            const size_t base = (size_t)(i0 + (s + 1) * SLAB) * 320;
            #pragma unroll
            for (int k = 0; k < 3; ++k) {
                const int idx = t + TPB * k;
                if (idx < SLAB * 320) pre[k] = Wt4[base + idx];
            }
        }

        #pragma unroll 1   // CRITICAL: full unroll multiplies w4 live range x4 -> spill
        for (int il = 0; il < SLAB; ++il) {
            const int i = i0 + s * SLAB + il;
            float4 w4[8];
            if (act) {
                #pragma unroll
                for (int j = 0; j < 8; ++j) w4[j] = slab[cur][il * 320 + j * 40 + q];
            }
            #pragma unroll
            for (int bb = 0; bb < BPW; ++bb) {
                const int b = b0 + bb;
                const float4* up = (const float4*)(u + ((size_t)b * 1152 + i) * 8);
                const float4 ua = up[0], ub = up[1];   // wave-uniform broadcast
                float4 uh;
                uh.x = dot8(w4[0], w4[1], ua, ub);
                uh.y = dot8(w4[2], w4[3], ua, ub);
                uh.z = dot8(w4[4], w4[5], ua, ub);
                uh.w = dot8(w4[6], w4[7], ua, ub);
                if (PASS == 0) {
                    sacc[bb].x += uh.x; sacc[bb].y += uh.y;
                    sacc[bb].z += uh.z; sacc[bb].w += uh.w;
                } else {
                    float pd = uh.x*va[bb].x + uh.y*va[bb].y
                             + uh.z*va[bb].z + uh.w*va[bb].w;
                    pd += __shfl_xor(pd, 1);
                    pd += __shfl_xor(pd, 2);           // full dot for this lane's c
                    const float e = act ? __expf(pd) : 0.0f;
                    float sm = e;
                    sm += __shfl_xor(sm, 4);
                    sm += __shfl_xor(sm, 8);
                    sm += __shfl_xor(sm, 16);
                    sm += __shfl_xor(sm, 32);          // = sum_c e_c
                    const float coef = e / sm;
                    sacc[bb].x += coef * uh.x; sacc[bb].y += coef * uh.y;
                    sacc[bb].z += coef * uh.z; sacc[bb].w += coef * uh.w;
                }
            }
        }

        if (more) {
            #pragma unroll
            for (int k = 0; k < 3; ++k) {
                const int idx = t + TPB * k;
                if (idx < SLAB * 320) slab[cur ^ 1][idx] = pre[k];
            }
        }
        __syncthreads();
        cur ^= 1;
    }

    // epilogue: non-atomic per-chunk partials, coalesced f4 stores
    if (act) {
        const float sc = (PASS == 0) ? 0.1f : 1.0f;
        #pragma unroll
        for (int bb = 0; bb < BPW; ++bb) {
            float4 o;
            o.x = sc * sacc[bb].x; o.y = sc * sacc[bb].y;
            o.z = sc * sacc[bb].z; o.w = sc * sacc[bb].w;
            ((float4*)part)[((size_t)ch * 512 + b0 + bb) * UHQ + q] = o;
        }
    }
}

// Sum NCHK partials and squash. 8 b-rows per block, grid 64.
__global__ void reduce_squash(const float* __restrict__ part, float* __restrict__ vout)
{
    __shared__ float acc_s[8 * 160];
    const int t  = threadIdx.x;
    const int b0 = blockIdx.x * 8;

    float acc[5] = {0.f, 0.f, 0.f, 0.f, 0.f};
    for (int ch = 0; ch < NCHK; ++ch) {
        const float* p = part + ((size_t)ch * 512 + b0) * 160;
        #pragma unroll
        for (int j = 0; j < 5; ++j) acc[j] += p[t + 256 * j];
    }
    #pragma unroll
    for (int j = 0; j < 5; ++j) acc_s[t + 256 * j] = acc[j];
    __syncthreads();

    if (t < 80) {   // 8 b x 10 c rows
        float sv[16];
        float ns = 0.0f;
        #pragma unroll
        for (int d = 0; d < 16; ++d) {
            float x = acc_s[t * 16 + d];
            sv[d] = x;
            ns += x * x;
        }
        float scale = ns / ((1.0f + ns) * (sqrtf(ns) + 1e-8f));
        float* o = vout + ((size_t)b0 * 10 + t) * 16;
        #pragma unroll
        for (int d = 0; d < 16; ++d) o[d] = sv[d] * scale;
    }
}

// ---------------- tiny-ws fallback (R3-style) ----------------
__global__ void squash_only(const float* __restrict__ s, float* __restrict__ vout)
{
    int r = blockIdx.x * 256 + threadIdx.x;
    if (r >= 512 * 10) return;
    const float* sp = s + (size_t)r * 16;
    float sv[16];
    float ns = 0.0f;
    #pragma unroll
    for (int d = 0; d < 16; ++d) {
        float x = sp[d];
        sv[d] = x;
        ns += x * x;
    }
    float scale = ns / ((1.0f + ns) * (sqrtf(ns) + 1e-8f));
    float* o = vout + (size_t)r * 16;
    #pragma unroll
    for (int d = 0; d < 16; ++d) o[d] = sv[d] * scale;
}

__device__ __forceinline__ float dot8p(const float* __restrict__ w,
                                       const float4 ua, const float4 ub) {
    const float4* wp = (const float4*)w;
    const float4 w0 = wp[0];
    const float4 w1 = wp[1];
    return w0.x*ua.x + w0.y*ua.y + w0.z*ua.z + w0.w*ua.w
         + w1.x*ub.x + w1.y*ub.y + w1.z*ub.z + w1.w*ub.w;
}

template <int PASS>
__global__ __launch_bounds__(256, 4)
void pass_fb(const float* __restrict__ u, const float* __restrict__ W,
             const float* __restrict__ v0g, const float* __restrict__ v1g,
             float* __restrict__ s_atomic)
{
    const int t    = threadIdx.x;
    const int lane = t & 63;
    const int wv   = t >> 6;
    const int bsub = lane / 10;
    const int c    = lane - bsub * 10;
    const bool lane_ok = (bsub < 6);
    const int b    = blockIdx.y * 24 + wv * 6 + bsub;
    const bool valid = lane_ok && (b < 512);
    const int bc   = valid ? b : 511;
    const int base = lane_ok ? bsub * 10 : 0;
    const int i0   = blockIdx.x * 24;

    float v[16];
    #pragma unroll
    for (int d = 0; d < 16; ++d) v[d] = 0.0f;
    if (PASS >= 1) {
        const float* vp = v0g + ((size_t)bc * 10 + c) * 16;
        #pragma unroll
        for (int d = 0; d < 16; ++d) v[d] = vp[d];
        if (PASS >= 2) {
            const float* vq = v1g + ((size_t)bc * 10 + c) * 16;
            #pragma unroll
            for (int d = 0; d < 16; ++d) v[d] += vq[d];
        }
    }

    float s_acc[16];
    #pragma unroll
    for (int d = 0; d < 16; ++d) s_acc[d] = 0.0f;

    for (int ii = 0; ii < 24; ++ii) {
        const int i = i0 + ii;
        const float4* up = (const float4*)(u + ((size_t)bc * 1152 + i) * 8);
        const float4 ua = up[0];
        const float4 ub = up[1];
        const float* Wp = W + ((size_t)i * 10 + c) * 128;

        float h[16];
        #pragma unroll
        for (int d = 0; d < 16; ++d) h[d] = dot8p(Wp + d * 8, ua, ub);

        if (PASS == 0) {
            #pragma unroll
            for (int d = 0; d < 16; ++d) s_acc[d] += h[d];
        } else {
            float lg = 0.0f;
            #pragma unroll
            for (int d = 0; d < 16; ++d) lg += h[d] * v[d];
            float lj[10];
            #pragma unroll
            for (int j = 0; j < 10; ++j) lj[j] = __shfl(lg, base + j);
            float m = lj[0];
            #pragma unroll
            for (int j = 1; j < 10; ++j) m = fmaxf(m, lj[j]);
            float sum = 0.0f;
            #pragma unroll
            for (int j = 0; j < 10; ++j) sum += __expf(lj[j] - m);
            const float coef = __expf(lg - m) / sum;
            #pragma unroll
            for (int d = 0; d < 16; ++d) s_acc[d] += coef * h[d];
        }
    }
    if (PASS == 0) {
        #pragma unroll
        for (int d = 0; d < 16; ++d) s_acc[d] *= 0.1f;
    }
    if (valid) {
#if defined(__HIP_DEVICE_COMPILE__)
        #pragma unroll
        for (int d = 0; d < 16; ++d)
            unsafeAtomicAdd(&s_atomic[((size_t)b * 10 + c) * 16 + d], s_acc[d]);
#endif
    }
}

extern "C" void kernel_launch(void* const* d_in, const int* in_sizes, int n_in,
                              void* d_out, int out_size, void* d_ws, size_t ws_size,
                              hipStream_t stream)
{
    const float* u = (const float*)d_in[0];   // [512,1152,8]
    const float* W = (const float*)d_in[1];   // [1152,10,16,8]
    float* out = (float*)d_out;               // [512,10,16]

    float* v0 = (float*)d_ws;                          // 81920 f32
    float* v1 = v0 + 81920;                            // 81920 f32
    float* wt = v1 + 81920;                            // 1,474,560 f32 (5.9 MB)
    float* part = wt + (size_t)1152 * 1280;            // 32*512*160 f32 (10.5 MB)

    const size_t need = ((size_t)2 * 81920 + (size_t)1152 * 1280
                         + (size_t)NCHK * 512 * 160) * sizeof(float);   // ~17 MB

    dim3 blk(256);
    dim3 blk2(TPB);

    if (ws_size >= need) {
        transpose_W<<<1440, blk, 0, stream>>>((const float4*)W, (float4*)wt);
        fused_pass<0><<<512, blk2, 0, stream>>>(u, wt, nullptr, nullptr, part);
        reduce_squash<<<64, blk, 0, stream>>>(part, v0);
        fused_pass<1><<<512, blk2, 0, stream>>>(u, wt, v0, nullptr, part);
        reduce_squash<<<64, blk, 0, stream>>>(part, v1);
        fused_pass<2><<<512, blk2, 0, stream>>>(u, wt, v0, v1, part);
        reduce_squash<<<64, blk, 0, stream>>>(part, out);
    } else {
        float* s0 = wt;                   // reuse low ws as atomic s buffers
        float* s1 = s0 + 81920;
        float* s2 = s1 + 81920;
        hipMemsetAsync(s0, 0, (size_t)3 * 81920 * sizeof(float), stream);
        dim3 grid(48, 22);
        pass_fb<0><<<grid, blk, 0, stream>>>(u, W, nullptr, nullptr, s0);
        squash_only<<<20, blk, 0, stream>>>(s0, v0);
        pass_fb<1><<<grid, blk, 0, stream>>>(u, W, v0, nullptr, s1);
        squash_only<<<20, blk, 0, stream>>>(s1, v1);
        pass_fb<2><<<grid, blk, 0, stream>>>(u, W, v0, v1, s2);
        squash_only<<<20, blk, 0, stream>>>(s2, out);
    }
}